// Round 2
// baseline (227.390 us; speedup 1.0000x reference)
//
#include <hip/hip_runtime.h>
#include <math.h>

// Problem constants
#define BB 2
#define HH 64
#define WW 64
#define DM 192
#define DI 384
#define NS 16
#define DTR 12
#define LL 4096
#define ROWS (BB*LL)   // 8192
#define NCHUNK 128
#define LCHUNK 32      // NCHUNK*LCHUNK == LL
#define NCOMBP 512     // padded combined-weight rows (416 real, zero-filled)
#define CSTRIDE ((size_t)BB * DI * 8)   // float2 elems per chunk slab

typedef __attribute__((ext_vector_type(8))) short bf16x8;
typedef __attribute__((ext_vector_type(4))) float f32x4;

typedef __attribute__((address_space(3))) void        as3_void;
typedef __attribute__((address_space(1))) const void  as1_cvoid;

// async global->LDS, 16B per lane; LDS dest = wave-uniform base + lane*16
__device__ __forceinline__ void gl_lds16(const unsigned short* g, unsigned short* l) {
    __builtin_amdgcn_global_load_lds((as1_cvoid*)g, (as3_void*)l, 16, 0, 0);
}

__device__ __forceinline__ float silu_f(float v) {
    return v / (1.0f + __expf(-v));
}

// fp32 -> bf16 (RNE) bit trick
__device__ __forceinline__ unsigned short f2bf(float f) {
    union { float f; unsigned int u; } c; c.f = f;
    unsigned int u = c.u;
    u += 0x7fffu + ((u >> 16) & 1u);
    return (unsigned short)(u >> 16);
}
__device__ __forceinline__ float bf2f(unsigned short h) {
    union { unsigned int u; float f; } c; c.u = ((unsigned int)h) << 16;
    return c.f;
}

// ---------------------------------------------------------------------------
// One prep kernel: cast W_in/W_con/W_out/x/cond to bf16 AND build combined
// weight Wc[512][384] (rows 0..383 = dt_w @ x_proj_w[:12], 384..415 = B/C,
// 416..511 zero pad).
// ---------------------------------------------------------------------------
__global__ __launch_bounds__(256) void prep_weights(
    const float* __restrict__ x, const float* __restrict__ cond,
    const float* __restrict__ w_in, const float* __restrict__ w_con,
    const float* __restrict__ w_out,
    const float* __restrict__ x_proj_w, const float* __restrict__ dt_w,
    unsigned short* __restrict__ w_in_bf, unsigned short* __restrict__ w_con_bf,
    unsigned short* __restrict__ w_out_bf, unsigned short* __restrict__ wc,
    unsigned short* __restrict__ x_bfo, unsigned short* __restrict__ c_bfo)
{
    int idx = blockIdx.x * 256 + threadIdx.x;
    if (idx < 73728) {
        const float4* src; ushort4* dst; int off;
        if (idx < 36864)      { src = (const float4*)w_in;  dst = (ushort4*)w_in_bf;  off = idx; }
        else if (idx < 55296) { src = (const float4*)w_con; dst = (ushort4*)w_con_bf; off = idx - 36864; }
        else                  { src = (const float4*)w_out; dst = (ushort4*)w_out_bf; off = idx - 55296; }
        float4 v = src[off];
        ushort4 o;
        o.x = f2bf(v.x); o.y = f2bf(v.y); o.z = f2bf(v.z); o.w = f2bf(v.w);
        dst[off] = o;
    } else if (idx < 73728 + NCOMBP * DI) {
        int e = idx - 73728;
        int row = e / DI, k = e - row * DI;
        float v = 0.f;
        if (row < 384) {
            const float* dw = dt_w + row * DTR;
            #pragma unroll
            for (int r = 0; r < DTR; ++r) v += dw[r] * x_proj_w[r * DI + k];
        } else if (row < 416) {
            v = x_proj_w[(12 + (row - 384)) * DI + k];
        }
        wc[e] = f2bf(v);
    } else if (idx < 73728 + NCOMBP * DI + 786432) {
        int e = idx - (73728 + NCOMBP * DI);   // < 2*393216 float4s
        const float4* src; ushort4* dst; int off;
        if (e < 393216) { src = (const float4*)x;    dst = (ushort4*)x_bfo; off = e; }
        else            { src = (const float4*)cond; dst = (ushort4*)c_bfo; off = e - 393216; }
        float4 v = src[off];
        ushort4 o;
        o.x = f2bf(v.x); o.y = f2bf(v.y); o.z = f2bf(v.z); o.w = f2bf(v.w);
        dst[off] = o;
    }
}

// ---------------------------------------------------------------------------
// Dual input GEMM, 128x128 tile, BK=32, lds-direct staging, K=192.
// z=0: xz = x @ W_in.T (xa->bf16, z->silu bf16, N=768)
// z=1: c = cond @ W_con.T (bf16, N=384)
// ---------------------------------------------------------------------------
__global__ __launch_bounds__(256) void gemm_in(
    const unsigned short* __restrict__ x_bf, const unsigned short* __restrict__ cin_bf,
    const unsigned short* __restrict__ w_in_bf,
    const unsigned short* __restrict__ w_con_bf,
    unsigned short* __restrict__ xa_bf, unsigned short* __restrict__ z_bf,
    unsigned short* __restrict__ c_bf)
{
    const int zz = blockIdx.z;
    if (zz == 1 && blockIdx.y >= 3) return;
    const unsigned short* A = zz ? cin_bf : x_bf;
    const unsigned short* W = zz ? w_con_bf : w_in_bf;

    __shared__ __align__(16) unsigned short sA[128 * 32];
    __shared__ __align__(16) unsigned short sB[128 * 32];
    const int bm = blockIdx.x * 128;
    const int bn = blockIdx.y * 128;
    const int tid  = threadIdx.x;
    const int wave = tid >> 6;
    const int lane = tid & 63;
    const int quad = lane >> 4;
    const int l16  = lane & 15;
    const int srow = tid >> 2;          // 0..63
    const int scol = (tid & 3) * 8;     // ushort col

    f32x4 acc[2][8];
    #pragma unroll
    for (int rf = 0; rf < 2; ++rf)
        #pragma unroll
        for (int t = 0; t < 8; ++t) acc[rf][t] = (f32x4)(0.f);

    const unsigned short* gA0 = &A[(size_t)(bm + srow) * DM + scol];
    const unsigned short* gA1 = gA0 + (size_t)64 * DM;
    const unsigned short* gB0 = &W[(size_t)(bn + srow) * DM + scol];
    const unsigned short* gB1 = gB0 + (size_t)64 * DM;
    unsigned short* lA0 = &sA[wave * 512];
    unsigned short* lA1 = &sA[2048 + wave * 512];
    unsigned short* lB0 = &sB[wave * 512];
    unsigned short* lB1 = &sB[2048 + wave * 512];

    const int ar0 = (wave * 32 + l16) * 32 + quad * 8;
    const int ar1 = ar0 + 16 * 32;

    for (int k0 = 0; k0 < DM; k0 += 32) {
        gl_lds16(gA0 + k0, lA0);
        gl_lds16(gA1 + k0, lA1);
        gl_lds16(gB0 + k0, lB0);
        gl_lds16(gB1 + k0, lB1);
        __syncthreads();
        bf16x8 a0 = *(bf16x8*)&sA[ar0];
        bf16x8 a1 = *(bf16x8*)&sA[ar1];
        #pragma unroll
        for (int t = 0; t < 8; ++t) {
            bf16x8 b = *(bf16x8*)&sB[(t * 16 + l16) * 32 + quad * 8];
            acc[0][t] = __builtin_amdgcn_mfma_f32_16x16x32_bf16(a0, b, acc[0][t], 0, 0, 0);
            acc[1][t] = __builtin_amdgcn_mfma_f32_16x16x32_bf16(a1, b, acc[1][t], 0, 0, 0);
        }
        __syncthreads();
    }

    #pragma unroll
    for (int rf = 0; rf < 2; ++rf) {
        #pragma unroll
        for (int t = 0; t < 8; ++t) {
            int col = bn + t * 16 + l16;
            #pragma unroll
            for (int r = 0; r < 4; ++r) {
                int row = bm + wave * 32 + rf * 16 + quad * 4 + r;
                float v = acc[rf][t][r];
                if (zz == 0) {
                    if (col < 384) xa_bf[(size_t)row * 384 + col] = f2bf(v);
                    else           z_bf[(size_t)row * 384 + (col - 384)] = f2bf(silu_f(v));
                } else {
                    c_bf[(size_t)row * 384 + col] = f2bf(v);
                }
            }
        }
    }
}

// ---------------------------------------------------------------------------
// Combined GEMM, 128x128 tile, BK=32, lds-direct, K=384, N=512 (padded).
// col<384 -> LOW ushort of du = bf16(softplus(v+bias));
// col in [384,416) -> packed btct floats; col >= 416 discarded.
// ---------------------------------------------------------------------------
__global__ __launch_bounds__(256) void gemm_comb(
    const unsigned short* __restrict__ A, const unsigned short* __restrict__ W,
    const float* __restrict__ bias, float* __restrict__ btct,
    unsigned short* __restrict__ du_lo)
{
    __shared__ __align__(16) unsigned short sA[128 * 32];
    __shared__ __align__(16) unsigned short sB[128 * 32];
    const int bm = blockIdx.x * 128;
    const int bn = blockIdx.y * 128;
    const int tid  = threadIdx.x;
    const int wave = tid >> 6;
    const int lane = tid & 63;
    const int quad = lane >> 4;
    const int l16  = lane & 15;
    const int srow = tid >> 2;
    const int scol = (tid & 3) * 8;

    f32x4 acc[2][8];
    #pragma unroll
    for (int rf = 0; rf < 2; ++rf)
        #pragma unroll
        for (int t = 0; t < 8; ++t) acc[rf][t] = (f32x4)(0.f);

    const unsigned short* gA0 = &A[(size_t)(bm + srow) * DI + scol];
    const unsigned short* gA1 = gA0 + (size_t)64 * DI;
    const unsigned short* gB0 = &W[(size_t)(bn + srow) * DI + scol];
    const unsigned short* gB1 = gB0 + (size_t)64 * DI;
    unsigned short* lA0 = &sA[wave * 512];
    unsigned short* lA1 = &sA[2048 + wave * 512];
    unsigned short* lB0 = &sB[wave * 512];
    unsigned short* lB1 = &sB[2048 + wave * 512];

    const int ar0 = (wave * 32 + l16) * 32 + quad * 8;
    const int ar1 = ar0 + 16 * 32;

    for (int k0 = 0; k0 < DI; k0 += 32) {
        gl_lds16(gA0 + k0, lA0);
        gl_lds16(gA1 + k0, lA1);
        gl_lds16(gB0 + k0, lB0);
        gl_lds16(gB1 + k0, lB1);
        __syncthreads();
        bf16x8 a0 = *(bf16x8*)&sA[ar0];
        bf16x8 a1 = *(bf16x8*)&sA[ar1];
        #pragma unroll
        for (int t = 0; t < 8; ++t) {
            bf16x8 b = *(bf16x8*)&sB[(t * 16 + l16) * 32 + quad * 8];
            acc[0][t] = __builtin_amdgcn_mfma_f32_16x16x32_bf16(a0, b, acc[0][t], 0, 0, 0);
            acc[1][t] = __builtin_amdgcn_mfma_f32_16x16x32_bf16(a1, b, acc[1][t], 0, 0, 0);
        }
        __syncthreads();
    }

    #pragma unroll
    for (int rf = 0; rf < 2; ++rf) {
        #pragma unroll
        for (int t = 0; t < 8; ++t) {
            int col = bn + t * 16 + l16;
            #pragma unroll
            for (int r = 0; r < 4; ++r) {
                int row = bm + wave * 32 + rf * 16 + quad * 4 + r;
                float v = acc[rf][t][r];
                if (col < 384) {
                    float a = v + bias[col];
                    float sp = (a > 20.f) ? a : log1pf(__expf(a));
                    du_lo[((size_t)row * 384 + col) * 2] = f2bf(sp);
                } else if (col < 416) {
                    int idx = col - 384;
                    int pos = (idx < 16) ? ((idx & 7) * 4 + (idx >> 3))
                                         : (((idx - 16) & 7) * 4 + 2 + ((idx - 16) >> 3));
                    btct[(size_t)row * 32 + pos] = v;
                }
            }
        }
    }
}

// ---------------------------------------------------------------------------
// Fused LN + z-mul + output GEMM. Grid (ROWS/64, DM/64) = (128, 3), 256 thr.
// Each block gathers its 64 A-rows from yt (scan order via rev_scan_path),
// computes LayerNorm + affine + z-mul in registers, writes bf16 A-tile into
// padded LDS, then runs the K=384 MFMA loop with lds-direct B staging.
// out = LN(yt[rev])*z @ W_out.T (fp32 out).
// ---------------------------------------------------------------------------
__global__ __launch_bounds__(256) void gemm_out_fused(
    const unsigned short* __restrict__ yt, const unsigned short* __restrict__ z,
    const int* __restrict__ rev_path,
    const float* __restrict__ ln_w, const float* __restrict__ ln_b,
    const unsigned short* __restrict__ W, float* __restrict__ out)
{
    __shared__ __align__(16) unsigned short sA[64 * 392];  // +8 pad: 784B stride
    __shared__ __align__(16) unsigned short sB[64 * 32];
    const int bm = blockIdx.x * 64;
    const int bn = blockIdx.y * 64;
    const int tid = threadIdx.x;
    const int r   = tid >> 2;      // 0..63 : row within tile
    const int q4  = tid & 3;       // 4 lanes per row
    const int b   = bm >> 12;      // LL = 4096
    const int l   = (bm & (LL - 1)) + r;
    const int js  = rev_path[l];

    const unsigned short* yrow = yt + ((size_t)(b * LL + js)) * DI;
    const unsigned short* zrow = z  + ((size_t)(b * LL + l)) * DI;

    // pass 1: row sums (interleaved 64B segments: lane q4 takes c = i*32+q4*8)
    float s = 0.f, s2 = 0.f;
    #pragma unroll
    for (int i = 0; i < 12; ++i) {
        bf16x8 v = *(const bf16x8*)&yrow[i * 32 + q4 * 8];
        #pragma unroll
        for (int e = 0; e < 8; ++e) {
            float f = bf2f((unsigned short)v[e]);
            s += f; s2 += f * f;
        }
    }
    s  += __shfl_xor(s, 1);  s  += __shfl_xor(s, 2);
    s2 += __shfl_xor(s2, 1); s2 += __shfl_xor(s2, 2);
    const float mu  = s * (1.0f / DI);
    const float inv = rsqrtf(s2 * (1.0f / DI) - mu * mu + 1e-5f);

    // pass 2: normalize * ln affine * z -> bf16 A-tile in LDS
    #pragma unroll
    for (int i = 0; i < 12; ++i) {
        int c = i * 32 + q4 * 8;
        bf16x8 v  = *(const bf16x8*)&yrow[c];
        bf16x8 zv = *(const bf16x8*)&zrow[c];
        float4 wa = *(const float4*)&ln_w[c];
        float4 wb = *(const float4*)&ln_w[c + 4];
        float4 ba = *(const float4*)&ln_b[c];
        float4 bb = *(const float4*)&ln_b[c + 4];
        bf16x8 o;
        o[0] = (short)f2bf(((bf2f((unsigned short)v[0]) - mu) * inv * wa.x + ba.x) * bf2f((unsigned short)zv[0]));
        o[1] = (short)f2bf(((bf2f((unsigned short)v[1]) - mu) * inv * wa.y + ba.y) * bf2f((unsigned short)zv[1]));
        o[2] = (short)f2bf(((bf2f((unsigned short)v[2]) - mu) * inv * wa.z + ba.z) * bf2f((unsigned short)zv[2]));
        o[3] = (short)f2bf(((bf2f((unsigned short)v[3]) - mu) * inv * wa.w + ba.w) * bf2f((unsigned short)zv[3]));
        o[4] = (short)f2bf(((bf2f((unsigned short)v[4]) - mu) * inv * wb.x + bb.x) * bf2f((unsigned short)zv[4]));
        o[5] = (short)f2bf(((bf2f((unsigned short)v[5]) - mu) * inv * wb.y + bb.y) * bf2f((unsigned short)zv[5]));
        o[6] = (short)f2bf(((bf2f((unsigned short)v[6]) - mu) * inv * wb.z + bb.z) * bf2f((unsigned short)zv[6]));
        o[7] = (short)f2bf(((bf2f((unsigned short)v[7]) - mu) * inv * wb.w + bb.w) * bf2f((unsigned short)zv[7]));
        *(bf16x8*)&sA[r * 392 + c] = o;
    }

    // MFMA K-loop
    const int wave = tid >> 6;
    const int lane = tid & 63;
    const int quad = lane >> 4;
    const int l16  = lane & 15;

    f32x4 acc[4];
    #pragma unroll
    for (int t = 0; t < 4; ++t) acc[t] = (f32x4)(0.f);

    const unsigned short* gB = &W[(size_t)(bn + r) * DI + q4 * 8];
    unsigned short* lB = &sB[wave * 512];
    const int abase = (wave * 16 + l16) * 392 + quad * 8;

    for (int k0 = 0; k0 < DI; k0 += 32) {
        gl_lds16(gB + k0, lB);
        __syncthreads();
        bf16x8 a = *(bf16x8*)&sA[abase + k0];
        #pragma unroll
        for (int t = 0; t < 4; ++t) {
            bf16x8 bfr = *(bf16x8*)&sB[(t * 16 + l16) * 32 + quad * 8];
            acc[t] = __builtin_amdgcn_mfma_f32_16x16x32_bf16(a, bfr, acc[t], 0, 0, 0);
        }
        __syncthreads();
    }

    #pragma unroll
    for (int t = 0; t < 4; ++t) {
        int col = bn + t * 16 + l16;
        #pragma unroll
        for (int rr = 0; rr < 4; ++rr) {
            int row = bm + wave * 16 + quad * 4 + rr;
            out[(size_t)row * DM + col] = acc[t][rr];
        }
    }
}

// ---------------------------------------------------------------------------
// Fused depthwise 3x3 convs + bias + silu; inputs bf16, math fp32; writes
// u = silu(conv_x) into the HIGH ushort of du[row][d], and s (bf16),
// SCATTERED to scan order. 32-channel groups; grid (64, 12, B).
// ---------------------------------------------------------------------------
__global__ __launch_bounds__(256) void dwconv2_scatter(
    const unsigned short* __restrict__ xin, const unsigned short* __restrict__ cin,
    const float* __restrict__ wx, const float* __restrict__ bx,
    const float* __restrict__ wc, const float* __restrict__ bc,
    const int* __restrict__ rev_scan_path,
    unsigned short* __restrict__ du_hi,   // ushort* view of du; write idx*2+1
    unsigned short* __restrict__ s_bf)
{
    const int tile = blockIdx.x;
    const int c0   = blockIdx.y * 32;
    const int b    = blockIdx.z;
    const int h0 = (tile >> 3) * 8, w0 = (tile & 7) * 8;
    __shared__ float smx[10 * 10 * 32];
    __shared__ float smc[10 * 10 * 32];
    __shared__ int   jtile[64];

    for (int idx = threadIdx.x; idx < 3200; idx += 256) {
        int pix = idx >> 5, ch = idx & 31;
        int py = pix / 10, px = pix - py * 10;
        int gh = h0 + py - 1, gw = w0 + px - 1;
        float vx = 0.f, vc = 0.f;
        if (gh >= 0 && gh < 64 && gw >= 0 && gw < 64) {
            size_t g = ((size_t)(b * LL + gh * 64 + gw)) * DI + c0 + ch;
            vx = bf2f(xin[g]); vc = bf2f(cin[g]);
        }
        smx[idx] = vx; smc[idx] = vc;
    }
    if (threadIdx.x < 64) {
        int l = (h0 + (threadIdx.x >> 3)) * 64 + (w0 + (threadIdx.x & 7));
        jtile[threadIdx.x] = rev_scan_path[l];
    }
    __syncthreads();

    const int ch = threadIdx.x & 31;
    const int pq = threadIdx.x >> 5;   // 0..7
    float wrx[9], wrc[9];
    #pragma unroll
    for (int k = 0; k < 9; ++k) {
        wrx[k] = wx[(c0 + ch) * 9 + k];
        wrc[k] = wc[(c0 + ch) * 9 + k];
    }
    const float bvx = bx[c0 + ch];
    const float bvc = bc[c0 + ch];

    #pragma unroll
    for (int i = 0; i < 8; ++i) {
        int p  = pq * 8 + i;           // 0..63
        int ph = p >> 3, pw = p & 7;
        float ax = bvx, ac = bvc;
        #pragma unroll
        for (int ki = 0; ki < 3; ++ki)
            #pragma unroll
            for (int kj = 0; kj < 3; ++kj) {
                int si = ((ph + ki) * 10 + (pw + kj)) * 32 + ch;
                ax += wrx[ki * 3 + kj] * smx[si];
                ac += wrc[ki * 3 + kj] * smc[si];
            }
        float xv = silu_f(ax);
        float sv = xv + silu_f(ac);
        size_t o = ((size_t)(b * LL + jtile[p])) * DI + c0 + ch;
        du_hi[o * 2 + 1] = f2bf(xv);
        s_bf[o]          = f2bf(sv);
    }
}

// ---------------------------------------------------------------------------
// Pass A: per-chunk composite, register-prefetch. (delta,u) packed in one
// uint stream -> 2 loads/step. grid (NCHUNK, DI/32, BB). Composite layout
// CHUNK-MAJOR. Chunk decay = exp(Av * sum(delta)).
// ---------------------------------------------------------------------------
__global__ __launch_bounds__(256) void scan_chunkA(
    const unsigned int* __restrict__ du, const float* __restrict__ btct,
    const float* __restrict__ A_logs,
    float* __restrict__ chunkA, float* __restrict__ chunkB)
{
    const int c = blockIdx.x;
    const int g = blockIdx.y;
    const int b = blockIdx.z;
    const int t = threadIdx.x;
    const int grp = t >> 3, p = t & 7;
    const int d = g * 32 + grp;
    const float Av0 = -__expf(A_logs[d * NS + p]);
    const float Av1 = -__expf(A_logs[d * NS + p + 8]);
    const int j0 = c * LCHUNK;

    const unsigned int* dul = du + ((size_t)b * LL + j0) * DI + d;
    const float2*       bl  = (const float2*)btct + ((size_t)b * LL + j0) * 16 + p * 2;

    float h0 = 0.f, h1 = 0.f, Sd = 0.f;
    unsigned int duv[4]; float2 bv[4];
    #pragma unroll
    for (int q = 0; q < 4; ++q) {
        duv[q] = dul[(size_t)q * DI]; bv[q] = bl[(size_t)q * 16];
    }
    for (int j = 0; j < LCHUNK; j += 4) {
        unsigned int ndu[4]; float2 nb[4];
        if (j + 4 < LCHUNK) {
            #pragma unroll
            for (int q = 0; q < 4; ++q) {
                int jj = j + 4 + q;
                ndu[q] = dul[(size_t)jj * DI]; nb[q] = bl[(size_t)jj * 16];
            }
        }
        #pragma unroll
        for (int q = 0; q < 4; ++q) {
            float dv = bf2f((unsigned short)(duv[q] & 0xffff));
            float uv = bf2f((unsigned short)(duv[q] >> 16));
            float e0 = __expf(dv * Av0);
            float e1 = __expf(dv * Av1);
            float duu = dv * uv;
            h0 = e0 * h0 + bv[q].x * duu;
            h1 = e1 * h1 + bv[q].y * duu;
            Sd += dv;
        }
        #pragma unroll
        for (int q = 0; q < 4; ++q) { duv[q]=ndu[q]; bv[q]=nb[q]; }
    }
    size_t idx = (size_t)c * CSTRIDE + ((size_t)b * DI + d) * 8 + p;
    ((float2*)chunkA)[idx] = make_float2(__expf(Sd * Av0), __expf(Sd * Av1));
    ((float2*)chunkB)[idx] = make_float2(h0, h1);
}

// ---------------------------------------------------------------------------
// Pass C: local scan seeded by an INLINE backward fold over the chunk-major
// composites (coalesced, early exit on underflow). (delta,u) packed; y bf16.
// ---------------------------------------------------------------------------
__global__ __launch_bounds__(256) void scan_chunkC(
    const unsigned int* __restrict__ du, const float* __restrict__ btct,
    const float* __restrict__ A_logs, const float* __restrict__ Ds,
    const float* __restrict__ chunkA, const float* __restrict__ chunkB,
    unsigned short* __restrict__ yt)
{
    const int c = blockIdx.x;
    const int g = blockIdx.y;
    const int b = blockIdx.z;
    const int t = threadIdx.x;
    const int grp = t >> 3, p = t & 7;
    const int d = g * 32 + grp;
    const float Av0 = -__expf(A_logs[d * NS + p]);
    const float Av1 = -__expf(A_logs[d * NS + p + 8]);
    const float Dv = Ds[d];
    const int j0 = c * LCHUNK;

    const unsigned int* dul = du + ((size_t)b * LL + j0) * DI + d;
    const float4*       bcl = (const float4*)btct + ((size_t)b * LL + j0) * 8 + p;
    unsigned short* yl = yt + ((size_t)b * LL + j0) * DI + d;

    const size_t off = ((size_t)b * DI + d) * 8 + p;
    const float2* A2 = (const float2*)chunkA;
    const float2* B2 = (const float2*)chunkB;
    float h0 = 0.f, h1 = 0.f, P0 = 1.f, P1 = 1.f;
    for (int i = c - 1; i >= 0; --i) {
        size_t ix = (size_t)i * CSTRIDE + off;
        float2 a = A2[ix], bv = B2[ix];
        h0 += P0 * bv.x;  h1 += P1 * bv.y;
        P0 *= a.x;        P1 *= a.y;
        if (fmaxf(fabsf(P0), fabsf(P1)) < 1e-30f) break;
    }

    unsigned int duv[4]; float4 bc[4];
    #pragma unroll
    for (int q = 0; q < 4; ++q) {
        duv[q] = dul[(size_t)q * DI]; bc[q] = bcl[(size_t)q * 8];
    }
    for (int j = 0; j < LCHUNK; j += 4) {
        unsigned int ndu[4]; float4 nbc[4];
        if (j + 4 < LCHUNK) {
            #pragma unroll
            for (int q = 0; q < 4; ++q) {
                int jj = j + 4 + q;
                ndu[q] = dul[(size_t)jj * DI]; nbc[q] = bcl[(size_t)jj * 8];
            }
        }
        #pragma unroll
        for (int q = 0; q < 4; ++q) {
            float dv = bf2f((unsigned short)(duv[q] & 0xffff));
            float uv = bf2f((unsigned short)(duv[q] >> 16));
            float e0 = __expf(dv * Av0);
            float e1 = __expf(dv * Av1);
            float duu = dv * uv;
            h0 = e0 * h0 + bc[q].x * duu;
            h1 = e1 * h1 + bc[q].y * duu;
            float acc = h0 * bc[q].z + h1 * bc[q].w;
            acc += __shfl_xor(acc, 4, 8);
            acc += __shfl_xor(acc, 2, 8);
            acc += __shfl_xor(acc, 1, 8);
            if (p == 0) yl[(size_t)(j + q) * DI] = f2bf(acc + uv * Dv);
        }
        #pragma unroll
        for (int q = 0; q < 4; ++q) { duv[q]=ndu[q]; bc[q]=nbc[q]; }
    }
}

// ---------------------------------------------------------------------------
extern "C" void kernel_launch(void* const* d_in, const int* in_sizes, int n_in,
                              void* d_out, int out_size, void* d_ws, size_t ws_size,
                              hipStream_t stream) {
    const float* x          = (const float*)d_in[0];
    const float* cond       = (const float*)d_in[1];
    const float* W_in       = (const float*)d_in[2];
    const float* W_con      = (const float*)d_in[3];
    const float* conv_w     = (const float*)d_in[4];
    const float* conv_b     = (const float*)d_in[5];
    const float* con_conv_w = (const float*)d_in[6];
    const float* con_conv_b = (const float*)d_in[7];
    const float* x_proj_w   = (const float*)d_in[8];
    const float* dt_proj_w  = (const float*)d_in[9];
    const float* dt_proj_b  = (const float*)d_in[10];
    const float* A_logs     = (const float*)d_in[11];
    const float* Ds         = (const float*)d_in[12];
    const float* ln_w       = (const float*)d_in[13];
    const float* ln_b       = (const float*)d_in[14];
    const float* W_out      = (const float*)d_in[15];
    const int*   scan_path  = (const int*)d_in[16];
    const int*   rev_path   = (const int*)d_in[17];
    (void)scan_path;

    float* ws = (float*)d_ws;
    const size_t S  = (size_t)BB * LL * DI;            // 3,145,728 floats
    const size_t SC = (size_t)NCHUNK * BB * DI * NS;   // 1,572,864 floats
    float* ytslab  = ws + 0 * S;                       // yt_bf (ushort, half used)
    float* zslab   = ws + 1 * S;                       // z_bf (ushort, half used)
    float* duslab  = ws + 2 * S;                       // du (uint, full slab)
    float* btct    = ws + 3 * S;                       // BB*LL*32 floats, packed
    float* chunkA  = btct + (size_t)BB * LL * 32;
    float* chunkB  = chunkA + SC;
    float* bfpool  = chunkB + SC;                      // bf16 staging area

    unsigned short* yt_bf    = (unsigned short*)ytslab;            // ROWS*DI
    unsigned short* z_bf     = (unsigned short*)zslab;             // ROWS*DI
    unsigned int*   du       = (unsigned int*)duslab;              // ROWS*DI uints
    unsigned short* s_bf     = (unsigned short*)bfpool;            // ROWS*DI
    unsigned short* xa_bf    = s_bf + (size_t)ROWS * DI;           // ROWS*DI
    unsigned short* c_bf     = xa_bf + (size_t)ROWS * DI;          // ROWS*DI
    unsigned short* w_in_bf  = c_bf + (size_t)ROWS * DI;           // 768*192
    unsigned short* w_con_bf = w_in_bf + 768 * DM;                 // 384*192
    unsigned short* w_out_bf = w_con_bf + 384 * DM;                // 192*384
    unsigned short* wcomb_bf = w_out_bf + 192 * DI;                // 512*384
    unsigned short* x_bf2    = wcomb_bf + (size_t)NCOMBP * DI;     // ROWS*DM
    unsigned short* cin_bf2  = x_bf2 + (size_t)ROWS * DM;          // ROWS*DM

    // 0) weight prep (casts + combined weight + x/cond bf16 cast), one launch
    prep_weights<<<4128, 256, 0, stream>>>(
        x, cond, W_in, W_con, W_out, x_proj_w, dt_proj_w,
        w_in_bf, w_con_bf, w_out_bf, wcomb_bf, x_bf2, cin_bf2);

    // 1+2) dual GEMM (lds-direct, 128x128): xz = x @ W_in.T AND c = cond @ W_con.T
    gemm_in<<<dim3(ROWS / 128, 6, 2), 256, 0, stream>>>(
        x_bf2, cin_bf2, w_in_bf, w_con_bf, xa_bf, z_bf, c_bf);
    // 3) fused depthwise convs (bf16 in) + silu + scatter; u -> du high half
    dwconv2_scatter<<<dim3(64, 12, BB), 256, 0, stream>>>(
        xa_bf, c_bf, conv_w, conv_b, con_conv_w, con_conv_b,
        rev_path, (unsigned short*)du, s_bf);
    // 4) combined GEMM (128x128): delta (softplus -> du low half) + packed btct
    gemm_comb<<<dim3(ROWS / 128, NCOMBP / 128), 256, 0, stream>>>(
        s_bf, wcomb_bf, dt_proj_b, btct, (unsigned short*)du);
    // 5) chunked parallel scan: pass A, then pass C with coalesced inline fold
    scan_chunkA<<<dim3(NCHUNK, DI / 32, BB), 256, 0, stream>>>(
        du, btct, A_logs, chunkA, chunkB);
    scan_chunkC<<<dim3(NCHUNK, DI / 32, BB), 256, 0, stream>>>(
        du, btct, A_logs, Ds, chunkA, chunkB, yt_bf);
    // 6+7) fused LN + z-mul + out GEMM: out = LN(yt[rev])*z @ W_out.T
    gemm_out_fused<<<dim3(ROWS / 64, DM / 64), 256, 0, stream>>>(
        yt_bf, z_bf, rev_path, ln_w, ln_b, w_out_bf, (float*)d_out);
}

// Round 3
// 202.912 us; speedup vs baseline: 1.1206x; 1.1206x over previous
//
#include <hip/hip_runtime.h>
#include <math.h>

// Problem constants
#define BB 2
#define HH 64
#define WW 64
#define DM 192
#define DI 384
#define NS 16
#define DTR 12
#define LL 4096
#define ROWS (BB*LL)   // 8192
#define NCHUNK 128
#define LCHUNK 32      // NCHUNK*LCHUNK == LL
#define NCOMB 448      // padded combined-weight rows (416 real)
#define CSTRIDE ((size_t)BB * DI * 8)   // float2 elems per chunk slab

typedef __attribute__((ext_vector_type(8))) short bf16x8;
typedef __attribute__((ext_vector_type(4))) float f32x4;

typedef __attribute__((address_space(3))) void        as3_void;
typedef __attribute__((address_space(1))) const void  as1_cvoid;

// async global->LDS, 16B per lane; LDS dest = wave-uniform base + lane*16
__device__ __forceinline__ void gl_lds16(const unsigned short* g, unsigned short* l) {
    __builtin_amdgcn_global_load_lds((as1_cvoid*)g, (as3_void*)l, 16, 0, 0);
}

__device__ __forceinline__ float silu_f(float v) {
    return v / (1.0f + __expf(-v));
}

// fp32 -> bf16 (RNE) bit trick
__device__ __forceinline__ unsigned short f2bf(float f) {
    union { float f; unsigned int u; } c; c.f = f;
    unsigned int u = c.u;
    u += 0x7fffu + ((u >> 16) & 1u);
    return (unsigned short)(u >> 16);
}
__device__ __forceinline__ float bf2f(unsigned short h) {
    union { unsigned int u; float f; } c; c.u = ((unsigned int)h) << 16;
    return c.f;
}

// ---------------------------------------------------------------------------
// One prep kernel: cast W_in/W_con/W_out/x/cond to bf16 AND build combined
// weight Wc[448][384] (rows 0..383 = dt_w @ x_proj_w[:12], 384..415 = B/C).
// ---------------------------------------------------------------------------
__global__ __launch_bounds__(256) void prep_weights(
    const float* __restrict__ x, const float* __restrict__ cond,
    const float* __restrict__ w_in, const float* __restrict__ w_con,
    const float* __restrict__ w_out,
    const float* __restrict__ x_proj_w, const float* __restrict__ dt_w,
    unsigned short* __restrict__ w_in_bf, unsigned short* __restrict__ w_con_bf,
    unsigned short* __restrict__ w_out_bf, unsigned short* __restrict__ wc,
    unsigned short* __restrict__ x_bfo, unsigned short* __restrict__ c_bfo)
{
    int idx = blockIdx.x * 256 + threadIdx.x;
    if (idx < 73728) {
        const float4* src; ushort4* dst; int off;
        if (idx < 36864)      { src = (const float4*)w_in;  dst = (ushort4*)w_in_bf;  off = idx; }
        else if (idx < 55296) { src = (const float4*)w_con; dst = (ushort4*)w_con_bf; off = idx - 36864; }
        else                  { src = (const float4*)w_out; dst = (ushort4*)w_out_bf; off = idx - 55296; }
        float4 v = src[off];
        ushort4 o;
        o.x = f2bf(v.x); o.y = f2bf(v.y); o.z = f2bf(v.z); o.w = f2bf(v.w);
        dst[off] = o;
    } else if (idx < 73728 + NCOMB * DI) {
        int e = idx - 73728;
        int row = e / DI, k = e - row * DI;
        float v = 0.f;
        if (row < 384) {
            const float* dw = dt_w + row * DTR;
            #pragma unroll
            for (int r = 0; r < DTR; ++r) v += dw[r] * x_proj_w[r * DI + k];
        } else if (row < 416) {
            v = x_proj_w[(12 + (row - 384)) * DI + k];
        }
        wc[e] = f2bf(v);
    } else if (idx < 73728 + NCOMB * DI + 786432) {
        int e = idx - (73728 + NCOMB * DI);   // < 2*393216 float4s
        const float4* src; ushort4* dst; int off;
        if (e < 393216) { src = (const float4*)x;    dst = (ushort4*)x_bfo; off = e; }
        else            { src = (const float4*)cond; dst = (ushort4*)c_bfo; off = e - 393216; }
        float4 v = src[off];
        ushort4 o;
        o.x = f2bf(v.x); o.y = f2bf(v.y); o.z = f2bf(v.z); o.w = f2bf(v.w);
        dst[off] = o;
    }
}

// ---------------------------------------------------------------------------
// Dual input GEMM, 128x64 tile, BK=32, double-buffered lds-direct staging
// with XOR bank swizzle, K=192.
// z=0: xz = x @ W_in.T (xa->bf16, z->silu bf16, N=768)
// z=1: c = cond @ W_con.T (bf16, N=384)
// ---------------------------------------------------------------------------
__global__ __launch_bounds__(256) void gemm_in(
    const unsigned short* __restrict__ x_bf, const unsigned short* __restrict__ cin_bf,
    const unsigned short* __restrict__ w_in_bf,
    const unsigned short* __restrict__ w_con_bf,
    unsigned short* __restrict__ xa_bf, unsigned short* __restrict__ z_bf,
    unsigned short* __restrict__ c_bf)
{
    const int zz = blockIdx.z;
    if (zz == 1 && blockIdx.y >= 6) return;
    const unsigned short* A = zz ? cin_bf : x_bf;
    const unsigned short* W = zz ? w_con_bf : w_in_bf;

    __shared__ __align__(16) unsigned short sA[2 * 128 * 32];
    __shared__ __align__(16) unsigned short sB[2 * 64 * 32];
    const int bm = blockIdx.x * 128;
    const int bn = blockIdx.y * 64;
    const int tid  = threadIdx.x;
    const int wave = tid >> 6;
    const int lane = tid & 63;
    const int quad = lane >> 4;
    const int l16  = lane & 15;
    const int srow = tid >> 2;                                  // 0..63
    const int scol = ((tid & 3) ^ ((tid >> 3) & 3)) * 8;        // swizzled fetch col
    const int rswz = (quad ^ ((l16 >> 1) & 3)) * 8;             // swizzled read col

    f32x4 acc[2][4];
    #pragma unroll
    for (int rf = 0; rf < 2; ++rf)
        #pragma unroll
        for (int t = 0; t < 4; ++t) acc[rf][t] = (f32x4)(0.f);

    const unsigned short* gA0 = &A[(size_t)(bm + srow) * DM + scol];
    const unsigned short* gA1 = gA0 + (size_t)64 * DM;
    const unsigned short* gB  = &W[(size_t)(bn + srow) * DM + scol];

    // prologue: stage k0=0 into buf 0
    gl_lds16(gA0, &sA[wave * 512]);
    gl_lds16(gA1, &sA[2048 + wave * 512]);
    gl_lds16(gB,  &sB[wave * 512]);
    __syncthreads();

    const int ar0 = (wave * 32 + l16) * 32 + rswz;
    const int ar1 = ar0 + 16 * 32;

    for (int t = 0; t < 6; ++t) {
        const int cur = t & 1;
        if (t + 1 < 6) {
            const int k = (t + 1) * 32;
            const int nb = cur ^ 1;
            gl_lds16(gA0 + k, &sA[nb * 4096 + wave * 512]);
            gl_lds16(gA1 + k, &sA[nb * 4096 + 2048 + wave * 512]);
            gl_lds16(gB  + k, &sB[nb * 2048 + wave * 512]);
        }
        const unsigned short* cA = &sA[cur * 4096];
        const unsigned short* cB = &sB[cur * 2048];
        bf16x8 a0 = *(bf16x8*)&cA[ar0];
        bf16x8 a1 = *(bf16x8*)&cA[ar1];
        #pragma unroll
        for (int n = 0; n < 4; ++n) {
            bf16x8 b = *(bf16x8*)&cB[(n * 16 + l16) * 32 + rswz];
            acc[0][n] = __builtin_amdgcn_mfma_f32_16x16x32_bf16(a0, b, acc[0][n], 0, 0, 0);
            acc[1][n] = __builtin_amdgcn_mfma_f32_16x16x32_bf16(a1, b, acc[1][n], 0, 0, 0);
        }
        __syncthreads();
    }

    #pragma unroll
    for (int rf = 0; rf < 2; ++rf) {
        #pragma unroll
        for (int t = 0; t < 4; ++t) {
            int col = bn + t * 16 + l16;
            #pragma unroll
            for (int r = 0; r < 4; ++r) {
                int row = bm + wave * 32 + rf * 16 + quad * 4 + r;
                float v = acc[rf][t][r];
                if (zz == 0) {
                    if (col < 384) xa_bf[(size_t)row * 384 + col] = f2bf(v);
                    else           z_bf[(size_t)row * 384 + (col - 384)] = f2bf(silu_f(v));
                } else {
                    c_bf[(size_t)row * 384 + col] = f2bf(v);
                }
            }
        }
    }
}

// ---------------------------------------------------------------------------
// Combined GEMM, 128x64 tile, BK=32, double-buffered lds-direct + swizzle,
// K=384, N=448 (padded).
// col<384 -> LOW ushort of du = bf16(softplus(v+bias));
// col in [384,416) -> packed btct floats; col >= 416 discarded.
// ---------------------------------------------------------------------------
__global__ __launch_bounds__(256) void gemm_comb(
    const unsigned short* __restrict__ A, const unsigned short* __restrict__ W,
    const float* __restrict__ bias, float* __restrict__ btct,
    unsigned short* __restrict__ du_lo)
{
    __shared__ __align__(16) unsigned short sA[2 * 128 * 32];
    __shared__ __align__(16) unsigned short sB[2 * 64 * 32];
    const int bm = blockIdx.x * 128;
    const int bn = blockIdx.y * 64;
    const int tid  = threadIdx.x;
    const int wave = tid >> 6;
    const int lane = tid & 63;
    const int quad = lane >> 4;
    const int l16  = lane & 15;
    const int srow = tid >> 2;
    const int scol = ((tid & 3) ^ ((tid >> 3) & 3)) * 8;
    const int rswz = (quad ^ ((l16 >> 1) & 3)) * 8;

    f32x4 acc[2][4];
    #pragma unroll
    for (int rf = 0; rf < 2; ++rf)
        #pragma unroll
        for (int t = 0; t < 4; ++t) acc[rf][t] = (f32x4)(0.f);

    const unsigned short* gA0 = &A[(size_t)(bm + srow) * DI + scol];
    const unsigned short* gA1 = gA0 + (size_t)64 * DI;
    const unsigned short* gB  = &W[(size_t)(bn + srow) * DI + scol];

    gl_lds16(gA0, &sA[wave * 512]);
    gl_lds16(gA1, &sA[2048 + wave * 512]);
    gl_lds16(gB,  &sB[wave * 512]);
    __syncthreads();

    const int ar0 = (wave * 32 + l16) * 32 + rswz;
    const int ar1 = ar0 + 16 * 32;

    for (int t = 0; t < 12; ++t) {
        const int cur = t & 1;
        if (t + 1 < 12) {
            const int k = (t + 1) * 32;
            const int nb = cur ^ 1;
            gl_lds16(gA0 + k, &sA[nb * 4096 + wave * 512]);
            gl_lds16(gA1 + k, &sA[nb * 4096 + 2048 + wave * 512]);
            gl_lds16(gB  + k, &sB[nb * 2048 + wave * 512]);
        }
        const unsigned short* cA = &sA[cur * 4096];
        const unsigned short* cB = &sB[cur * 2048];
        bf16x8 a0 = *(bf16x8*)&cA[ar0];
        bf16x8 a1 = *(bf16x8*)&cA[ar1];
        #pragma unroll
        for (int n = 0; n < 4; ++n) {
            bf16x8 b = *(bf16x8*)&cB[(n * 16 + l16) * 32 + rswz];
            acc[0][n] = __builtin_amdgcn_mfma_f32_16x16x32_bf16(a0, b, acc[0][n], 0, 0, 0);
            acc[1][n] = __builtin_amdgcn_mfma_f32_16x16x32_bf16(a1, b, acc[1][n], 0, 0, 0);
        }
        __syncthreads();
    }

    #pragma unroll
    for (int rf = 0; rf < 2; ++rf) {
        #pragma unroll
        for (int t = 0; t < 4; ++t) {
            int col = bn + t * 16 + l16;
            #pragma unroll
            for (int r = 0; r < 4; ++r) {
                int row = bm + wave * 32 + rf * 16 + quad * 4 + r;
                float v = acc[rf][t][r];
                if (col < 384) {
                    float a = v + bias[col];
                    float sp = (a > 20.f) ? a : log1pf(__expf(a));
                    du_lo[((size_t)row * 384 + col) * 2] = f2bf(sp);
                } else if (col < 416) {
                    int idx = col - 384;
                    int pos = (idx < 16) ? ((idx & 7) * 4 + (idx >> 3))
                                         : (((idx - 16) & 7) * 4 + 2 + ((idx - 16) >> 3));
                    btct[(size_t)row * 32 + pos] = v;
                }
            }
        }
    }
}

// ---------------------------------------------------------------------------
// Fused LN + z-mul + output GEMM. Grid (ROWS/64, DM/64) = (128, 3), 256 thr.
// Each block gathers its 64 A-rows from yt (scan order via rev_scan_path),
// computes LayerNorm + affine + z-mul in registers, writes bf16 A-tile into
// padded LDS, then runs the K=384 MFMA loop with double-buffered lds-direct
// B staging (+swizzle). out = LN(yt[rev])*z @ W_out.T (fp32 out).
// ---------------------------------------------------------------------------
__global__ __launch_bounds__(256) void gemm_out_fused(
    const unsigned short* __restrict__ yt, const unsigned short* __restrict__ z,
    const int* __restrict__ rev_path,
    const float* __restrict__ ln_w, const float* __restrict__ ln_b,
    const unsigned short* __restrict__ W, float* __restrict__ out)
{
    __shared__ __align__(16) unsigned short sA[64 * 392];  // +8 pad: 784B stride
    __shared__ __align__(16) unsigned short sB[2 * 64 * 32];
    const int bm = blockIdx.x * 64;
    const int bn = blockIdx.y * 64;
    const int tid = threadIdx.x;
    const int r   = tid >> 2;      // 0..63 : row within tile
    const int q4  = tid & 3;       // 4 lanes per row
    const int b   = bm >> 12;      // LL = 4096
    const int l   = (bm & (LL - 1)) + r;
    const int js  = rev_path[l];

    const unsigned short* yrow = yt + ((size_t)(b * LL + js)) * DI;
    const unsigned short* zrow = z  + ((size_t)(b * LL + l)) * DI;

    // pass 1: row sums (interleaved 64B segments: lane q4 takes c = i*32+q4*8)
    float s = 0.f, s2 = 0.f;
    #pragma unroll
    for (int i = 0; i < 12; ++i) {
        bf16x8 v = *(const bf16x8*)&yrow[i * 32 + q4 * 8];
        #pragma unroll
        for (int e = 0; e < 8; ++e) {
            float f = bf2f((unsigned short)v[e]);
            s += f; s2 += f * f;
        }
    }
    s  += __shfl_xor(s, 1);  s  += __shfl_xor(s, 2);
    s2 += __shfl_xor(s2, 1); s2 += __shfl_xor(s2, 2);
    const float mu  = s * (1.0f / DI);
    const float inv = rsqrtf(s2 * (1.0f / DI) - mu * mu + 1e-5f);

    // pass 2: normalize * ln affine * z -> bf16 A-tile in LDS
    #pragma unroll
    for (int i = 0; i < 12; ++i) {
        int c = i * 32 + q4 * 8;
        bf16x8 v  = *(const bf16x8*)&yrow[c];
        bf16x8 zv = *(const bf16x8*)&zrow[c];
        float4 wa = *(const float4*)&ln_w[c];
        float4 wb = *(const float4*)&ln_w[c + 4];
        float4 ba = *(const float4*)&ln_b[c];
        float4 bb = *(const float4*)&ln_b[c + 4];
        bf16x8 o;
        o[0] = (short)f2bf(((bf2f((unsigned short)v[0]) - mu) * inv * wa.x + ba.x) * bf2f((unsigned short)zv[0]));
        o[1] = (short)f2bf(((bf2f((unsigned short)v[1]) - mu) * inv * wa.y + ba.y) * bf2f((unsigned short)zv[1]));
        o[2] = (short)f2bf(((bf2f((unsigned short)v[2]) - mu) * inv * wa.z + ba.z) * bf2f((unsigned short)zv[2]));
        o[3] = (short)f2bf(((bf2f((unsigned short)v[3]) - mu) * inv * wa.w + ba.w) * bf2f((unsigned short)zv[3]));
        o[4] = (short)f2bf(((bf2f((unsigned short)v[4]) - mu) * inv * wb.x + bb.x) * bf2f((unsigned short)zv[4]));
        o[5] = (short)f2bf(((bf2f((unsigned short)v[5]) - mu) * inv * wb.y + bb.y) * bf2f((unsigned short)zv[5]));
        o[6] = (short)f2bf(((bf2f((unsigned short)v[6]) - mu) * inv * wb.z + bb.z) * bf2f((unsigned short)zv[6]));
        o[7] = (short)f2bf(((bf2f((unsigned short)v[7]) - mu) * inv * wb.w + bb.w) * bf2f((unsigned short)zv[7]));
        *(bf16x8*)&sA[r * 392 + c] = o;
    }

    // MFMA K-loop (double-buffered B staging)
    const int wave = tid >> 6;
    const int lane = tid & 63;
    const int quad = lane >> 4;
    const int l16  = lane & 15;
    const int scol = ((tid & 3) ^ ((tid >> 3) & 3)) * 8;
    const int rswz = (quad ^ ((l16 >> 1) & 3)) * 8;

    f32x4 acc[4];
    #pragma unroll
    for (int t = 0; t < 4; ++t) acc[t] = (f32x4)(0.f);

    const unsigned short* gB = &W[(size_t)(bn + r) * DI + scol];
    const int abase = (wave * 16 + l16) * 392 + quad * 8;

    gl_lds16(gB, &sB[wave * 512]);
    __syncthreads();   // covers sA ds_writes + buf0 B loads

    for (int t = 0; t < 12; ++t) {
        const int cur = t & 1;
        if (t + 1 < 12)
            gl_lds16(gB + (t + 1) * 32, &sB[(cur ^ 1) * 2048 + wave * 512]);
        bf16x8 a = *(bf16x8*)&sA[abase + t * 32];
        const unsigned short* cB = &sB[cur * 2048];
        #pragma unroll
        for (int n = 0; n < 4; ++n) {
            bf16x8 bfr = *(bf16x8*)&cB[(n * 16 + l16) * 32 + rswz];
            acc[n] = __builtin_amdgcn_mfma_f32_16x16x32_bf16(a, bfr, acc[n], 0, 0, 0);
        }
        __syncthreads();
    }

    #pragma unroll
    for (int t = 0; t < 4; ++t) {
        int col = bn + t * 16 + l16;
        #pragma unroll
        for (int rr = 0; rr < 4; ++rr) {
            int row = bm + wave * 16 + quad * 4 + rr;
            out[(size_t)row * DM + col] = acc[t][rr];
        }
    }
}

// ---------------------------------------------------------------------------
// Fused depthwise 3x3 convs + bias + silu; inputs bf16, math fp32; writes
// u = silu(conv_x) into the HIGH ushort of du[row][d], and s (bf16),
// SCATTERED to scan order. 32-channel groups; grid (64, 12, B).
// ---------------------------------------------------------------------------
__global__ __launch_bounds__(256) void dwconv2_scatter(
    const unsigned short* __restrict__ xin, const unsigned short* __restrict__ cin,
    const float* __restrict__ wx, const float* __restrict__ bx,
    const float* __restrict__ wc, const float* __restrict__ bc,
    const int* __restrict__ rev_scan_path,
    unsigned short* __restrict__ du_hi,   // ushort* view of du; write idx*2+1
    unsigned short* __restrict__ s_bf)
{
    const int tile = blockIdx.x;
    const int c0   = blockIdx.y * 32;
    const int b    = blockIdx.z;
    const int h0 = (tile >> 3) * 8, w0 = (tile & 7) * 8;
    __shared__ float smx[10 * 10 * 32];
    __shared__ float smc[10 * 10 * 32];
    __shared__ int   jtile[64];

    for (int idx = threadIdx.x; idx < 3200; idx += 256) {
        int pix = idx >> 5, ch = idx & 31;
        int py = pix / 10, px = pix - py * 10;
        int gh = h0 + py - 1, gw = w0 + px - 1;
        float vx = 0.f, vc = 0.f;
        if (gh >= 0 && gh < 64 && gw >= 0 && gw < 64) {
            size_t g = ((size_t)(b * LL + gh * 64 + gw)) * DI + c0 + ch;
            vx = bf2f(xin[g]); vc = bf2f(cin[g]);
        }
        smx[idx] = vx; smc[idx] = vc;
    }
    if (threadIdx.x < 64) {
        int l = (h0 + (threadIdx.x >> 3)) * 64 + (w0 + (threadIdx.x & 7));
        jtile[threadIdx.x] = rev_scan_path[l];
    }
    __syncthreads();

    const int ch = threadIdx.x & 31;
    const int pq = threadIdx.x >> 5;   // 0..7
    float wrx[9], wrc[9];
    #pragma unroll
    for (int k = 0; k < 9; ++k) {
        wrx[k] = wx[(c0 + ch) * 9 + k];
        wrc[k] = wc[(c0 + ch) * 9 + k];
    }
    const float bvx = bx[c0 + ch];
    const float bvc = bc[c0 + ch];

    #pragma unroll
    for (int i = 0; i < 8; ++i) {
        int p  = pq * 8 + i;           // 0..63
        int ph = p >> 3, pw = p & 7;
        float ax = bvx, ac = bvc;
        #pragma unroll
        for (int ki = 0; ki < 3; ++ki)
            #pragma unroll
            for (int kj = 0; kj < 3; ++kj) {
                int si = ((ph + ki) * 10 + (pw + kj)) * 32 + ch;
                ax += wrx[ki * 3 + kj] * smx[si];
                ac += wrc[ki * 3 + kj] * smc[si];
            }
        float xv = silu_f(ax);
        float sv = xv + silu_f(ac);
        size_t o = ((size_t)(b * LL + jtile[p])) * DI + c0 + ch;
        du_hi[o * 2 + 1] = f2bf(xv);
        s_bf[o]          = f2bf(sv);
    }
}

// ---------------------------------------------------------------------------
// Pass A: per-chunk composite, register-prefetch. (delta,u) packed in one
// uint stream -> 2 loads/step. grid (NCHUNK, DI/32, BB). Composite layout
// CHUNK-MAJOR. Chunk decay = exp(Av * sum(delta)).
// ---------------------------------------------------------------------------
__global__ __launch_bounds__(256) void scan_chunkA(
    const unsigned int* __restrict__ du, const float* __restrict__ btct,
    const float* __restrict__ A_logs,
    float* __restrict__ chunkA, float* __restrict__ chunkB)
{
    const int c = blockIdx.x;
    const int g = blockIdx.y;
    const int b = blockIdx.z;
    const int t = threadIdx.x;
    const int grp = t >> 3, p = t & 7;
    const int d = g * 32 + grp;
    const float Av0 = -__expf(A_logs[d * NS + p]);
    const float Av1 = -__expf(A_logs[d * NS + p + 8]);
    const int j0 = c * LCHUNK;

    const unsigned int* dul = du + ((size_t)b * LL + j0) * DI + d;
    const float2*       bl  = (const float2*)btct + ((size_t)b * LL + j0) * 16 + p * 2;

    float h0 = 0.f, h1 = 0.f, Sd = 0.f;
    unsigned int duv[4]; float2 bv[4];
    #pragma unroll
    for (int q = 0; q < 4; ++q) {
        duv[q] = dul[(size_t)q * DI]; bv[q] = bl[(size_t)q * 16];
    }
    for (int j = 0; j < LCHUNK; j += 4) {
        unsigned int ndu[4]; float2 nb[4];
        if (j + 4 < LCHUNK) {
            #pragma unroll
            for (int q = 0; q < 4; ++q) {
                int jj = j + 4 + q;
                ndu[q] = dul[(size_t)jj * DI]; nb[q] = bl[(size_t)jj * 16];
            }
        }
        #pragma unroll
        for (int q = 0; q < 4; ++q) {
            float dv = bf2f((unsigned short)(duv[q] & 0xffff));
            float uv = bf2f((unsigned short)(duv[q] >> 16));
            float e0 = __expf(dv * Av0);
            float e1 = __expf(dv * Av1);
            float duu = dv * uv;
            h0 = e0 * h0 + bv[q].x * duu;
            h1 = e1 * h1 + bv[q].y * duu;
            Sd += dv;
        }
        #pragma unroll
        for (int q = 0; q < 4; ++q) { duv[q]=ndu[q]; bv[q]=nb[q]; }
    }
    size_t idx = (size_t)c * CSTRIDE + ((size_t)b * DI + d) * 8 + p;
    ((float2*)chunkA)[idx] = make_float2(__expf(Sd * Av0), __expf(Sd * Av1));
    ((float2*)chunkB)[idx] = make_float2(h0, h1);
}

// ---------------------------------------------------------------------------
// Pass C: local scan seeded by an INLINE backward fold over the chunk-major
// composites (coalesced, early exit on underflow). (delta,u) packed; y bf16.
// ---------------------------------------------------------------------------
__global__ __launch_bounds__(256) void scan_chunkC(
    const unsigned int* __restrict__ du, const float* __restrict__ btct,
    const float* __restrict__ A_logs, const float* __restrict__ Ds,
    const float* __restrict__ chunkA, const float* __restrict__ chunkB,
    unsigned short* __restrict__ yt)
{
    const int c = blockIdx.x;
    const int g = blockIdx.y;
    const int b = blockIdx.z;
    const int t = threadIdx.x;
    const int grp = t >> 3, p = t & 7;
    const int d = g * 32 + grp;
    const float Av0 = -__expf(A_logs[d * NS + p]);
    const float Av1 = -__expf(A_logs[d * NS + p + 8]);
    const float Dv = Ds[d];
    const int j0 = c * LCHUNK;

    const unsigned int* dul = du + ((size_t)b * LL + j0) * DI + d;
    const float4*       bcl = (const float4*)btct + ((size_t)b * LL + j0) * 8 + p;
    unsigned short* yl = yt + ((size_t)b * LL + j0) * DI + d;

    const size_t off = ((size_t)b * DI + d) * 8 + p;
    const float2* A2 = (const float2*)chunkA;
    const float2* B2 = (const float2*)chunkB;
    float h0 = 0.f, h1 = 0.f, P0 = 1.f, P1 = 1.f;
    for (int i = c - 1; i >= 0; --i) {
        size_t ix = (size_t)i * CSTRIDE + off;
        float2 a = A2[ix], bv = B2[ix];
        h0 += P0 * bv.x;  h1 += P1 * bv.y;
        P0 *= a.x;        P1 *= a.y;
        if (fmaxf(fabsf(P0), fabsf(P1)) < 1e-30f) break;
    }

    unsigned int duv[4]; float4 bc[4];
    #pragma unroll
    for (int q = 0; q < 4; ++q) {
        duv[q] = dul[(size_t)q * DI]; bc[q] = bcl[(size_t)q * 8];
    }
    for (int j = 0; j < LCHUNK; j += 4) {
        unsigned int ndu[4]; float4 nbc[4];
        if (j + 4 < LCHUNK) {
            #pragma unroll
            for (int q = 0; q < 4; ++q) {
                int jj = j + 4 + q;
                ndu[q] = dul[(size_t)jj * DI]; nbc[q] = bcl[(size_t)jj * 8];
            }
        }
        #pragma unroll
        for (int q = 0; q < 4; ++q) {
            float dv = bf2f((unsigned short)(duv[q] & 0xffff));
            float uv = bf2f((unsigned short)(duv[q] >> 16));
            float e0 = __expf(dv * Av0);
            float e1 = __expf(dv * Av1);
            float duu = dv * uv;
            h0 = e0 * h0 + bc[q].x * duu;
            h1 = e1 * h1 + bc[q].y * duu;
            float acc = h0 * bc[q].z + h1 * bc[q].w;
            acc += __shfl_xor(acc, 4, 8);
            acc += __shfl_xor(acc, 2, 8);
            acc += __shfl_xor(acc, 1, 8);
            if (p == 0) yl[(size_t)(j + q) * DI] = f2bf(acc + uv * Dv);
        }
        #pragma unroll
        for (int q = 0; q < 4; ++q) { duv[q]=ndu[q]; bc[q]=nbc[q]; }
    }
}

// ---------------------------------------------------------------------------
extern "C" void kernel_launch(void* const* d_in, const int* in_sizes, int n_in,
                              void* d_out, int out_size, void* d_ws, size_t ws_size,
                              hipStream_t stream) {
    const float* x          = (const float*)d_in[0];
    const float* cond       = (const float*)d_in[1];
    const float* W_in       = (const float*)d_in[2];
    const float* W_con      = (const float*)d_in[3];
    const float* conv_w     = (const float*)d_in[4];
    const float* conv_b     = (const float*)d_in[5];
    const float* con_conv_w = (const float*)d_in[6];
    const float* con_conv_b = (const float*)d_in[7];
    const float* x_proj_w   = (const float*)d_in[8];
    const float* dt_proj_w  = (const float*)d_in[9];
    const float* dt_proj_b  = (const float*)d_in[10];
    const float* A_logs     = (const float*)d_in[11];
    const float* Ds         = (const float*)d_in[12];
    const float* ln_w       = (const float*)d_in[13];
    const float* ln_b       = (const float*)d_in[14];
    const float* W_out      = (const float*)d_in[15];
    const int*   scan_path  = (const int*)d_in[16];
    const int*   rev_path   = (const int*)d_in[17];
    (void)scan_path;

    float* ws = (float*)d_ws;
    const size_t S  = (size_t)BB * LL * DI;            // 3,145,728 floats
    const size_t SC = (size_t)NCHUNK * BB * DI * NS;   // 1,572,864 floats
    float* ytslab  = ws + 0 * S;                       // yt_bf (ushort, half used)
    float* zslab   = ws + 1 * S;                       // z_bf (ushort, half used)
    float* duslab  = ws + 2 * S;                       // du (uint, full slab)
    float* btct    = ws + 3 * S;                       // BB*LL*32 floats, packed
    float* chunkA  = btct + (size_t)BB * LL * 32;
    float* chunkB  = chunkA + SC;
    float* bfpool  = chunkB + SC;                      // bf16 staging area

    unsigned short* yt_bf    = (unsigned short*)ytslab;            // ROWS*DI
    unsigned short* z_bf     = (unsigned short*)zslab;             // ROWS*DI
    unsigned int*   du       = (unsigned int*)duslab;              // ROWS*DI uints
    unsigned short* s_bf     = (unsigned short*)bfpool;            // ROWS*DI
    unsigned short* xa_bf    = s_bf + (size_t)ROWS * DI;           // ROWS*DI
    unsigned short* c_bf     = xa_bf + (size_t)ROWS * DI;          // ROWS*DI
    unsigned short* w_in_bf  = c_bf + (size_t)ROWS * DI;           // 768*192
    unsigned short* w_con_bf = w_in_bf + 768 * DM;                 // 384*192
    unsigned short* w_out_bf = w_con_bf + 384 * DM;                // 192*384
    unsigned short* wcomb_bf = w_out_bf + 192 * DI;                // 448*384
    unsigned short* x_bf2    = wcomb_bf + (size_t)NCOMB * DI;      // ROWS*DM
    unsigned short* cin_bf2  = x_bf2 + (size_t)ROWS * DM;          // ROWS*DM

    // 0) weight prep (casts + combined weight + x/cond bf16 cast), one launch
    prep_weights<<<4032, 256, 0, stream>>>(
        x, cond, W_in, W_con, W_out, x_proj_w, dt_proj_w,
        w_in_bf, w_con_bf, w_out_bf, wcomb_bf, x_bf2, cin_bf2);

    // 1+2) dual GEMM (dbuf lds-direct, 128x64): xz = x @ W_in.T AND c = cond @ W_con.T
    gemm_in<<<dim3(ROWS / 128, 12, 2), 256, 0, stream>>>(
        x_bf2, cin_bf2, w_in_bf, w_con_bf, xa_bf, z_bf, c_bf);
    // 3) fused depthwise convs (bf16 in) + silu + scatter; u -> du high half
    dwconv2_scatter<<<dim3(64, 12, BB), 256, 0, stream>>>(
        xa_bf, c_bf, conv_w, conv_b, con_conv_w, con_conv_b,
        rev_path, (unsigned short*)du, s_bf);
    // 4) combined GEMM (dbuf, 128x64): delta (softplus -> du low half) + packed btct
    gemm_comb<<<dim3(ROWS / 128, NCOMB / 64), 256, 0, stream>>>(
        s_bf, wcomb_bf, dt_proj_b, btct, (unsigned short*)du);
    // 5) chunked parallel scan: pass A, then pass C with coalesced inline fold
    scan_chunkA<<<dim3(NCHUNK, DI / 32, BB), 256, 0, stream>>>(
        du, btct, A_logs, chunkA, chunkB);
    scan_chunkC<<<dim3(NCHUNK, DI / 32, BB), 256, 0, stream>>>(
        du, btct, A_logs, Ds, chunkA, chunkB, yt_bf);
    // 6+7) fused LN + z-mul + out GEMM: out = LN(yt[rev])*z @ W_out.T
    gemm_out_fused<<<dim3(ROWS / 64, DM / 64), 256, 0, stream>>>(
        yt_bf, z_bf, rev_path, ln_w, ln_b, w_out_bf, (float*)d_out);
}